// Round 2
// baseline (350.043 us; speedup 1.0000x reference)
//
#include <hip/hip_runtime.h>

// Problem constants (B=16, C1=C2=128, H=W=80, K=3, pad=1, stride=1)
#define HH 80
#define WW 80
#define C1 128
#define C2 128
#define NB 16
#define HWSZ 6400      // 80*80
#define KKT 1152       // C1*9 (GEMM K, reordered as k' = p*128 + c)

typedef __attribute__((ext_vector_type(8))) short bf16x8;
typedef __attribute__((ext_vector_type(4))) float f32x4;

__device__ inline ushort f2bf(float f) {
  unsigned u = __float_as_uint(f);
  return (ushort)((u + 0x7FFFu + ((u >> 16) & 1u)) >> 16);
}

// packed f32x2 -> bf16x2 (RNE, identical rounding to f2bf), 1 instr for 2 elems
__device__ inline uint cvtpk(float lo, float hi) {
  uint r;
  asm("v_cvt_pk_bf16_f32 %0, %1, %2" : "=v"(r) : "v"(lo), "v"(hi));
  return r;
}
__device__ inline float bfu_lo(uint w) { return __uint_as_float(w << 16); }
__device__ inline float bfu_hi(uint w) { return __uint_as_float(w & 0xFFFF0000u); }

// ---------------------------------------------------------------------------
// Kernel A: transpose x (b,c,hw) f32 -> xt (b,hw,c) bf16.  64hw x 64c tiles.
// ---------------------------------------------------------------------------
__global__ __launch_bounds__(256) void xpose_kernel(const float* __restrict__ x,
                                                    ushort* __restrict__ xt) {
  const int b = blockIdx.z;
  const int c0 = blockIdx.y * 64;
  const int hw0 = blockIdx.x * 64;
  const int tid = threadIdx.x;
  const int lane = tid & 63;

  __shared__ float ts[64][65];

  #pragma unroll
  for (int it = 0; it < 16; it++) {
    int cl = (tid >> 6) + it * 4;
    ts[cl][lane] = x[((size_t)(b * C1 + c0 + cl)) * HWSZ + hw0 + lane];
  }
  __syncthreads();

  #pragma unroll
  for (int it = 0; it < 2; it++) {
    int u = tid + it * 256;
    int j = u >> 3, cg = u & 7;
    union { uint4 v; uint w[4]; } pk;
    #pragma unroll
    for (int m = 0; m < 4; m++)
      pk.w[m] = cvtpk(ts[cg * 8 + 2 * m][j], ts[cg * 8 + 2 * m + 1][j]);
    *(uint4*)(xt + ((size_t)b * HWSZ + hw0 + j) * C1 + c0 + cg * 8) = pk.v;
  }
}

// ---------------------------------------------------------------------------
// Kernel B: combined weight prep.
//  wbf  [kt][kg][ch128][j] : main weights, k' = p*128+c order (147456)
//  wobf [kt][kg][ch32][j]  : offset-conv weights padded to 32 ch (36864)
// ---------------------------------------------------------------------------
__global__ __launch_bounds__(256) void prep_kernel(const float* __restrict__ w,
                                                   const float* __restrict__ ow,
                                                   ushort* __restrict__ wbf,
                                                   ushort* __restrict__ wobf) {
  int o = blockIdx.x * 256 + threadIdx.x;        // 184320 total
  if (o < C2 * KKT) {
    int j  = o & 7;
    int ch = (o >> 3) & 127;
    int kt = o >> 12;
    int kg = (o >> 10) & 3;
    int kprime = kt * 32 + kg * 8 + j;
    int p = kprime >> 7;
    int c = kprime & 127;
    wbf[o] = f2bf(w[(size_t)ch * KKT + c * 9 + p]);
  } else if (o < C2 * KKT + 32 * KKT) {
    int o2 = o - C2 * KKT;
    int j  = o2 & 7;
    int ch = (o2 >> 3) & 31;
    int kt = o2 >> 10;
    int kg = (o2 >> 8) & 3;
    int kprime = kt * 32 + kg * 8 + j;
    int p = kprime >> 7;
    int c = kprime & 127;
    wobf[o2] = (ch < 18) ? f2bf(ow[(size_t)ch * KKT + c * 9 + p]) : (ushort)0;
  }
}

// ---------------------------------------------------------------------------
// Kernel C (FUSED): offset conv + bilinear sampling + main MFMA, one kernel.
// ZERO __syncthreads: all LDS traffic is wave-private (lane (q,c15) of wave w
// produces/consumes only wave-w regions), weights come straight from global
// (L1/L2-resident, identical addresses across blocks), so every wave
// free-runs its own load->compute pipeline.  Latency is hidden by TLP
// instead of being exposed at a per-chunk all-wave vmcnt(0) drain.
// ---------------------------------------------------------------------------
struct Geo { float f00, f01, f10, f11; int o00, o01, o10, o11; };

__device__ inline Geo make_geo(float4 cd) {
  Geo g;
  int y0 = (int)cd.x, x0 = (int)cd.y;
  float wy1 = cd.z, wx1 = cd.w;
  float fy0 = ((unsigned)y0 < (unsigned)HH) ? (1.f - wy1) : 0.f;
  float fy1 = ((unsigned)(y0 + 1) < (unsigned)HH) ? wy1 : 0.f;
  float fx0 = ((unsigned)x0 < (unsigned)WW) ? (1.f - wx1) : 0.f;
  float fx1 = ((unsigned)(x0 + 1) < (unsigned)WW) ? wx1 : 0.f;
  g.f00 = fy0 * fx0; g.f01 = fy0 * fx1;
  g.f10 = fy1 * fx0; g.f11 = fy1 * fx1;
  int r0 = min(max(y0, 0), HH - 1), r1 = min(max(y0 + 1, 0), HH - 1);
  int q0 = min(max(x0, 0), WW - 1), q1 = min(max(x0 + 1, 0), WW - 1);
  g.o00 = (r0 * WW + q0) * C1; g.o01 = (r0 * WW + q1) * C1;
  g.o10 = (r1 * WW + q0) * C1; g.o11 = (r1 * WW + q1) * C1;
  return g;
}

__global__ __launch_bounds__(256) void dconv_fused_kernel(
    const ushort* __restrict__ xt, const ushort* __restrict__ wobf,
    const float* __restrict__ ob, const ushort* __restrict__ wbf,
    const float* __restrict__ bias, float* __restrict__ out) {
  const int bid = blockIdx.x;                    // 0..1599
  const int b = bid & 15;
  const int tile = bid >> 4;                     // 0..99
  const int h0 = (tile / 5) * 4;
  const int w0 = (tile % 5) * 16;
  const int tid = threadIdx.x;
  const int lane = tid & 63;
  const int wave = tid >> 6;
  const int q = lane >> 4, c15 = lane & 15;
  const int spos = wave * 16 + c15;

  __shared__ float offs_lds[4][18][16];          // 4608 B, wave-private rows
  __shared__ float4 crd[9][64];                  // 9216 B, wave-private cols

  const ushort* xtb = xt + (size_t)b * HWSZ * C1;

  auto shifted_load = [&](int kt) -> uint4 {
    const int p = kt >> 2, c0 = (kt & 3) << 5;
    const int row = h0 + wave + (p / 3) - 1;
    const int col = w0 + c15 + (p % 3) - 1;
    uint4 v = {0u, 0u, 0u, 0u};
    if ((unsigned)row < (unsigned)HH && (unsigned)col < (unsigned)WW)
      v = *(const uint4*)(xtb + ((size_t)row * WW + col) * C1 + c0 + q * 8);
    return v;
  };

  // ===== Phase 1: offset conv (18 ch, padded 32) for this tile's 64 pos =====
  {
    f32x4 acc0 = {0.f, 0.f, 0.f, 0.f}, acc1 = {0.f, 0.f, 0.f, 0.f};
    uint4 cv = shifted_load(0);

    #pragma unroll 4
    for (int kt = 0; kt < 36; ++kt) {
      uint4 nv = {0u, 0u, 0u, 0u};
      if (kt < 35) nv = shifted_load(kt + 1);

      bf16x8 a0 = *(const bf16x8*)(wobf + ((size_t)kt * 128 + q * 32 + c15) * 8);
      bf16x8 a1 = *(const bf16x8*)(wobf + ((size_t)kt * 128 + q * 32 + 16 + c15) * 8);
      union { uint4 v; bf16x8 h; } bu; bu.v = cv;
      acc0 = __builtin_amdgcn_mfma_f32_16x16x32_bf16(a0, bu.h, acc0, 0, 0, 0);
      acc1 = __builtin_amdgcn_mfma_f32_16x16x32_bf16(a1, bu.h, acc1, 0, 0, 0);
      cv = nv;
    }

    // write offsets to this wave's private LDS region.
    // D layout: col = c15 (pos), row = q*4+r (ch)
    #pragma unroll
    for (int r = 0; r < 4; r++) {
      int ch = q * 4 + r;                        // 0..15, all valid
      offs_lds[wave][ch][c15] = acc0[r] + ob[ch];
    }
    if (q == 0) {
      offs_lds[wave][16][c15] = acc1[0] + ob[16];
      offs_lds[wave][17][c15] = acc1[1] + ob[17];
    }
  }

  // ===== Phase A: per-(p,pos) coords, wave-private (p split across q) =====
  {
    const int ho = h0 + wave, wo = w0 + c15;
    #pragma unroll
    for (int p = 0; p < 9; ++p) {
      if ((p & 3) == q) {
        float dy = offs_lds[wave][2 * p][c15];
        float dx = offs_lds[wave][2 * p + 1][c15];
        float py = (float)(ho - 1 + p / 3) + dy;
        float px = (float)(wo - 1 + p % 3) + dx;
        float y0f = floorf(py), x0f = floorf(px);
        crd[p][spos] = make_float4(y0f, x0f, py - y0f, px - x0f);
      }
    }
  }

  // ===== Phase 2: bilinear sampling + main MFMA, barrier-free =====
  f32x4 acc[8];
  #pragma unroll
  for (int mt = 0; mt < 8; mt++) acc[mt] = (f32x4){0.f, 0.f, 0.f, 0.f};

  const int wlane = (q * 128 + c15) * 8;         // ushort offset into a chunk

  // pipeline prologue: geometry + corner gathers for chunk 0
  Geo g = make_geo(crd[0][spos]);
  uint4 ca00, ca01, ca10, ca11;
  {
    const ushort* cp = xtb + q * 8;              // c0 = 0
    ca00 = *(const uint4*)(cp + g.o00);
    ca01 = *(const uint4*)(cp + g.o01);
    ca10 = *(const uint4*)(cp + g.o10);
    ca11 = *(const uint4*)(cp + g.o11);
  }

  #pragma unroll 4
  for (int kt = 0; kt < 36; ++kt) {
    // ---- issue next chunk's corner gathers (overlaps this chunk's compute)
    Geo gn = g;
    uint4 na00 = {}, na01 = {}, na10 = {}, na11 = {};
    if (kt < 35) {
      const int kn = kt + 1;
      if ((kn & 3) == 0) gn = make_geo(crd[kn >> 2][spos]);
      const ushort* np = xtb + ((kn & 3) << 5) + q * 8;
      na00 = *(const uint4*)(np + gn.o00);
      na01 = *(const uint4*)(np + gn.o01);
      na10 = *(const uint4*)(np + gn.o10);
      na11 = *(const uint4*)(np + gn.o11);
    }

    // ---- weight frags straight from global (L1/L2-resident, no LDS)
    const ushort* wkt = wbf + (size_t)kt * 4096 + wlane;

    // ---- flat 4-corner bilinear combine; result IS the B fragment
    union { uint4 v; uint w[4]; } u00, u01, u10, u11;
    union { uint4 v; uint w[4]; bf16x8 h; } pk;
    u00.v = ca00; u01.v = ca01; u10.v = ca10; u11.v = ca11;
    #pragma unroll
    for (int jw = 0; jw < 4; ++jw) {
      float ol = g.f00 * bfu_lo(u00.w[jw]);
      float oh = g.f00 * bfu_hi(u00.w[jw]);
      ol = fmaf(g.f01, bfu_lo(u01.w[jw]), ol);
      oh = fmaf(g.f01, bfu_hi(u01.w[jw]), oh);
      ol = fmaf(g.f10, bfu_lo(u10.w[jw]), ol);
      oh = fmaf(g.f10, bfu_hi(u10.w[jw]), oh);
      ol = fmaf(g.f11, bfu_lo(u11.w[jw]), ol);
      oh = fmaf(g.f11, bfu_hi(u11.w[jw]), oh);
      pk.w[jw] = cvtpk(ol, oh);
    }

    // ---- MFMA: B frag from registers, 8 A frags from global
    #pragma unroll
    for (int mt = 0; mt < 8; mt++) {
      bf16x8 afrag = *(const bf16x8*)(wkt + mt * 128);
      acc[mt] = __builtin_amdgcn_mfma_f32_16x16x32_bf16(afrag, pk.h, acc[mt], 0, 0, 0);
    }

    // ---- rotate pipeline registers
    g = gn;
    ca00 = na00; ca01 = na01; ca10 = na10; ca11 = na11;
  }

  // ---- epilogue
  {
    const int ho = h0 + wave, wo = w0 + c15;
    #pragma unroll
    for (int mt = 0; mt < 8; mt++) {
      #pragma unroll
      for (int r = 0; r < 4; r++) {
        int ch = mt * 16 + q * 4 + r;
        out[((size_t)b * C2 + ch) * HWSZ + ho * WW + wo] = acc[mt][r] + bias[ch];
      }
    }
  }
}

// ---------------------------------------------------------------------------
extern "C" void kernel_launch(void* const* d_in, const int* in_sizes, int n_in,
                              void* d_out, int out_size, void* d_ws, size_t ws_size,
                              hipStream_t stream) {
  const float* x    = (const float*)d_in[0];   // (16,128,80,80)
  const float* ow   = (const float*)d_in[1];   // (18,128,3,3)
  const float* ob   = (const float*)d_in[2];   // (18,)
  const float* wgt  = (const float*)d_in[3];   // (128,128,3,3)
  const float* bias = (const float*)d_in[4];   // (128,)
  float* out = (float*)d_out;                  // (16,128,80,80)

  // workspace layout (xt first for 16B alignment)
  ushort* xt   = (ushort*)d_ws;                          // 26.2 MB
  ushort* wbf  = (ushort*)((char*)d_ws + 26214400);      // 288 KB
  ushort* wobf = (ushort*)((char*)d_ws + 26214400 + 294912);  // 72 KB

  prep_kernel<<<dim3(720), dim3(256), 0, stream>>>(wgt, ow, wbf, wobf);
  xpose_kernel<<<dim3(100, 2, NB), dim3(256), 0, stream>>>(x, xt);
  dconv_fused_kernel<<<dim3(1600), dim3(256), 0, stream>>>(xt, wobf, ob, wbf, bias, out);
}

// Round 3
// 289.349 us; speedup vs baseline: 1.2098x; 1.2098x over previous
//
#include <hip/hip_runtime.h>

// Problem constants (B=16, C1=C2=128, H=W=80, K=3, pad=1, stride=1)
#define HH 80
#define WW 80
#define C1 128
#define C2 128
#define NB 16
#define HWSZ 6400      // 80*80
#define KKT 1152       // C1*9 (GEMM K, reordered as k' = p*128 + c)

typedef __attribute__((ext_vector_type(8))) short bf16x8;
typedef __attribute__((ext_vector_type(4))) float f32x4;

__device__ inline ushort f2bf(float f) {
  unsigned u = __float_as_uint(f);
  return (ushort)((u + 0x7FFFu + ((u >> 16) & 1u)) >> 16);
}

// packed f32x2 -> bf16x2 (RNE, identical rounding to f2bf)
__device__ inline uint cvtpk(float lo, float hi) {
  uint r;
  asm("v_cvt_pk_bf16_f32 %0, %1, %2" : "=v"(r) : "v"(lo), "v"(hi));
  return r;
}
__device__ inline float bfu_lo(uint w) { return __uint_as_float(w << 16); }
__device__ inline float bfu_hi(uint w) { return __uint_as_float(w & 0xFFFF0000u); }

// async global->LDS, 16B per lane, LDS dest = uniform base + lane*16
__device__ inline void gload_lds16(const ushort* g, ushort* l) {
  __builtin_amdgcn_global_load_lds(
      (const __attribute__((address_space(1))) void*)g,
      (__attribute__((address_space(3))) void*)l, 16, 0, 0);
}

// ---------------------------------------------------------------------------
// Kernel A+B merged: transpose x -> xt (blocks 0..3199) and weight prep
// (blocks 3200..3919).  One launch boundary fewer.
// ---------------------------------------------------------------------------
__global__ __launch_bounds__(256) void xpose_prep_kernel(
    const float* __restrict__ x, ushort* __restrict__ xt,
    const float* __restrict__ w, const float* __restrict__ ow,
    ushort* __restrict__ wbf, ushort* __restrict__ wobf) {
  __shared__ float ts[64][65];
  const int idx = blockIdx.x;
  const int tid = threadIdx.x;

  if (idx < 3200) {
    // ---- transpose (b,c,hw) f32 -> (b,hw,c) bf16, 64hw x 64c tiles
    const int b = idx / 200;
    const int rem = idx % 200;
    const int c0 = (rem / 100) * 64;
    const int hw0 = (rem % 100) * 64;
    const int lane = tid & 63;

    #pragma unroll
    for (int it = 0; it < 16; it++) {
      int cl = (tid >> 6) + it * 4;
      ts[cl][lane] = x[((size_t)(b * C1 + c0 + cl)) * HWSZ + hw0 + lane];
    }
    __syncthreads();

    #pragma unroll
    for (int it = 0; it < 2; it++) {
      int u = tid + it * 256;
      int j = u >> 3, cg = u & 7;
      union { uint4 v; uint d[4]; } pk;
      #pragma unroll
      for (int m = 0; m < 4; m++)
        pk.d[m] = cvtpk(ts[cg * 8 + 2 * m][j], ts[cg * 8 + 2 * m + 1][j]);
      *(uint4*)(xt + ((size_t)b * HWSZ + hw0 + j) * C1 + c0 + cg * 8) = pk.v;
    }
  } else {
    // ---- weight prep
    int o = (idx - 3200) * 256 + tid;            // 0..184319
    if (o < C2 * KKT) {
      int j  = o & 7;
      int ch = (o >> 3) & 127;
      int kt = o >> 12;
      int kg = (o >> 10) & 3;
      int kprime = kt * 32 + kg * 8 + j;
      int p = kprime >> 7;
      int c = kprime & 127;
      wbf[o] = f2bf(w[(size_t)ch * KKT + c * 9 + p]);
    } else {
      int o2 = o - C2 * KKT;
      int j  = o2 & 7;
      int ch = (o2 >> 3) & 31;
      int kt = o2 >> 10;
      int kg = (o2 >> 8) & 3;
      int kprime = kt * 32 + kg * 8 + j;
      int p = kprime >> 7;
      int c = kprime & 127;
      wobf[o2] = (ch < 18) ? f2bf(ow[(size_t)ch * KKT + c * 9 + p]) : (ushort)0;
    }
  }
}

// ---------------------------------------------------------------------------
// Kernel C: offset conv (round-0 verbatim — known-good, ~30 us).
// ---------------------------------------------------------------------------
__global__ __launch_bounds__(256) void offset_mfma_kernel(
    const ushort* __restrict__ xt, const ushort* __restrict__ wobf,
    const float* __restrict__ ob, float* __restrict__ offs) {
  const int bid = blockIdx.x;                    // 0..1599
  const int b = bid & 15;
  const int tile = bid >> 4;                     // 0..99
  const int h0 = (tile / 5) * 4;
  const int w0 = (tile % 5) * 16;
  const int tid = threadIdx.x;
  const int lane = tid & 63;
  const int wave = tid >> 6;
  const int pl = lane & 15, cg = lane >> 4;
  const int spos = wave * 16 + pl;

  __shared__ ushort s_t[4][64][8];               // 4 KB
  __shared__ ushort w_t[4][32][8];               // 2 KB

  f32x4 acc0 = {0.f, 0.f, 0.f, 0.f}, acc1 = {0.f, 0.f, 0.f, 0.f};
  const ushort* xtb = xt + (size_t)b * HWSZ * C1;

  auto shifted_load = [&](int kt) -> uint4 {
    const int p = kt >> 2, c0 = (kt & 3) << 5;
    const int row = h0 + (spos >> 4) + (p / 3) - 1;
    const int col = w0 + (spos & 15) + (p % 3) - 1;
    uint4 v = {0u, 0u, 0u, 0u};
    if ((unsigned)row < (unsigned)HH && (unsigned)col < (unsigned)WW)
      v = *(const uint4*)(xtb + ((size_t)row * WW + col) * C1 + c0 + cg * 8);
    return v;
  };

  uint4 cv = shifted_load(0);
  uint4 cw = {0u, 0u, 0u, 0u};
  if (tid < 128) cw = ((const uint4*)wobf)[tid];

  #pragma unroll 4
  for (int kt = 0; kt < 36; ++kt) {
    uint4 nv = {0u, 0u, 0u, 0u}, nw = {0u, 0u, 0u, 0u};
    if (kt < 35) {
      nv = shifted_load(kt + 1);
      if (tid < 128) nw = ((const uint4*)(wobf + (size_t)(kt + 1) * 1024))[tid];
    }

    __syncthreads();
    ((uint4*)s_t)[cg * 64 + spos] = cv;
    if (tid < 128) ((uint4*)w_t)[tid] = cw;
    __syncthreads();

    const int q = lane >> 4, c15 = lane & 15;
    bf16x8 bfrag = *(const bf16x8*)&s_t[q][wave * 16 + c15][0];
    bf16x8 a0 = *(const bf16x8*)&w_t[q][c15][0];
    bf16x8 a1 = *(const bf16x8*)&w_t[q][16 + c15][0];
    acc0 = __builtin_amdgcn_mfma_f32_16x16x32_bf16(a0, bfrag, acc0, 0, 0, 0);
    acc1 = __builtin_amdgcn_mfma_f32_16x16x32_bf16(a1, bfrag, acc1, 0, 0, 0);

    cv = nv; cw = nw;
  }

  {
    const int q = lane >> 4, c15 = lane & 15;
    const int ho = h0 + wave, wo = w0 + c15;
    #pragma unroll
    for (int r = 0; r < 4; r++) {
      int ch = q * 4 + r;
      if (ch < 18)
        offs[((size_t)b * 18 + ch) * HWSZ + ho * WW + wo] = acc0[r] + ob[ch];
      int ch1 = 16 + q * 4 + r;
      if (ch1 < 18)
        offs[((size_t)b * 18 + ch1) * HWSZ + ho * WW + wo] = acc1[r] + ob[ch1];
    }
  }
}

// ---------------------------------------------------------------------------
// Kernel D: fused bilinear + MFMA with counted-vmcnt pipeline (T3/T4).
// Per chunk the wave issues exactly 6 vmem ops in pinned order:
//   [stage(kt+1): 2x global_load_lds] then [gathers(kt+2): 4x uint4].
// Loop head: s_waitcnt vmcnt(4) retires exactly {stage(kt), gathers(kt)}
// while leaving gathers(kt+1) in flight ACROSS the raw s_barrier — no
// vmcnt(0) drain anywhere in the main loop.  Weights stay in LDS
// (double-buffered) so L1 serves only the gathers.
// ---------------------------------------------------------------------------
struct Geo { float f00, f01, f10, f11; int o00, o01, o10, o11; };

__device__ inline Geo make_geo(float4 cd) {
  Geo g;
  int y0 = (int)cd.x, x0 = (int)cd.y;
  float wy1 = cd.z, wx1 = cd.w;
  float fy0 = ((unsigned)y0 < (unsigned)HH) ? (1.f - wy1) : 0.f;
  float fy1 = ((unsigned)(y0 + 1) < (unsigned)HH) ? wy1 : 0.f;
  float fx0 = ((unsigned)x0 < (unsigned)WW) ? (1.f - wx1) : 0.f;
  float fx1 = ((unsigned)(x0 + 1) < (unsigned)WW) ? wx1 : 0.f;
  g.f00 = fy0 * fx0; g.f01 = fy0 * fx1;
  g.f10 = fy1 * fx0; g.f11 = fy1 * fx1;
  int r0 = min(max(y0, 0), HH - 1), r1 = min(max(y0 + 1, 0), HH - 1);
  int q0 = min(max(x0, 0), WW - 1), q1 = min(max(x0 + 1, 0), WW - 1);
  g.o00 = (r0 * WW + q0) * C1; g.o01 = (r0 * WW + q1) * C1;
  g.o10 = (r1 * WW + q0) * C1; g.o11 = (r1 * WW + q1) * C1;
  return g;
}

__global__ __launch_bounds__(256) void dconv_mfma_kernel(
    const ushort* __restrict__ xt, const float* __restrict__ offs,
    const ushort* __restrict__ wbf, const float* __restrict__ bias,
    float* __restrict__ out) {
  const int bid = blockIdx.x;                    // 0..1599
  const int b = bid & 15;
  const int tile = bid >> 4;                     // 0..99
  const int h0 = (tile / 5) * 4;
  const int w0 = (tile % 5) * 16;
  const int tid = threadIdx.x;
  const int lane = tid & 63;
  const int wave = tid >> 6;
  const int q = lane >> 4, c15 = lane & 15;
  const int spos = wave * 16 + c15;

  __shared__ float4 crd[9][64];                  // 9216 B (wave-private use)
  __shared__ ushort w_buf[2][4096];              // 16 KB double-buffered

  const ushort* xtb = xt + (size_t)b * HWSZ * C1;

  // ---- Phase A: coords, wave-private (writer and reader in same wave)
  {
    const int ho = h0 + wave, wo = w0 + c15;
    const float* obp = offs + (size_t)b * 18 * HWSZ + ho * WW + wo;
    #pragma unroll
    for (int p = 0; p < 9; ++p) {
      if ((p & 3) == q) {
        float dy = obp[(size_t)(2 * p) * HWSZ];
        float dx = obp[(size_t)(2 * p + 1) * HWSZ];
        float py = (float)(ho - 1 + p / 3) + dy;
        float px = (float)(wo - 1 + p % 3) + dx;
        float y0f = floorf(py), x0f = floorf(px);
        crd[p][spos] = make_float4(y0f, x0f, py - y0f, px - x0f);
      }
    }
  }

  auto stage = [&](int kn) {
    #pragma unroll
    for (int jj = 0; jj < 2; ++jj)
      gload_lds16(wbf + ((size_t)kn * 512 + wave * 128 + jj * 64 + lane) * 8,
                  &w_buf[kn & 1][(wave * 128 + jj * 64) * 8]);
  };

  auto gload = [&](const Geo& gg, int c0,
                   uint4& r00, uint4& r01, uint4& r10, uint4& r11) {
    const ushort* cp = xtb + c0 + q * 8;
    r00 = *(const uint4*)(cp + gg.o00);
    r01 = *(const uint4*)(cp + gg.o01);
    r10 = *(const uint4*)(cp + gg.o10);
    r11 = *(const uint4*)(cp + gg.o11);
  };

  f32x4 acc[8];
  #pragma unroll
  for (int mt = 0; mt < 8; mt++) acc[mt] = (f32x4){0.f, 0.f, 0.f, 0.f};

  // ---- pipeline prologue.  vmem order matters: stage(0) OLDEST, then g0, g1.
  Geo gcur = make_geo(crd[0][spos]);
  Geo gnext = gcur;
  uint4 a00, a01, a10, a11;                      // chunk kt   corners
  uint4 b00, b01, b10, b11;                      // chunk kt+1 corners

  stage(0);
  asm volatile("" ::: "memory");                 // pin stage before gathers
  gload(gcur, 0,  a00, a01, a10, a11);
  gload(gcur, 32, b00, b01, b10, b11);

  // one chunk body.  LAST: final chunk (full drain).  HAVE1: stage kt+1
  // exists.  HAVE2: gathers kt+2 exist.  gld: geometry for the kt+2 loads.
  auto body = [&](int kt, const Geo& gld, bool LAST, bool HAVE1, bool HAVE2) {
    if (LAST) asm volatile("s_waitcnt vmcnt(0)" ::: "memory");
    else      asm volatile("s_waitcnt vmcnt(4)" ::: "memory");
    __builtin_amdgcn_s_barrier();
    asm volatile("" ::: "memory");               // pin: nothing crosses barrier
    if (HAVE1) stage(kt + 1);
    asm volatile("" ::: "memory");               // pin: stage before gathers
    uint4 n00, n01, n10, n11;
    if (HAVE2) gload(gld, ((kt + 2) & 3) << 5, n00, n01, n10, n11);

    // flat 4-corner bilinear on chunk kt (regs); result IS the B fragment
    union { uint4 v; uint d[4]; } u00, u01, u10, u11;
    union { uint4 v; uint d[4]; bf16x8 h; } pk;
    u00.v = a00; u01.v = a01; u10.v = a10; u11.v = a11;
    #pragma unroll
    for (int jw = 0; jw < 4; ++jw) {
      float ol = gcur.f00 * bfu_lo(u00.d[jw]);
      float oh = gcur.f00 * bfu_hi(u00.d[jw]);
      ol = fmaf(gcur.f01, bfu_lo(u01.d[jw]), ol);
      oh = fmaf(gcur.f01, bfu_hi(u01.d[jw]), oh);
      ol = fmaf(gcur.f10, bfu_lo(u10.d[jw]), ol);
      oh = fmaf(gcur.f10, bfu_hi(u10.d[jw]), oh);
      ol = fmaf(gcur.f11, bfu_lo(u11.d[jw]), ol);
      oh = fmaf(gcur.f11, bfu_hi(u11.d[jw]), oh);
      pk.d[jw] = cvtpk(ol, oh);
    }

    // MFMA: 8 A frags from w_buf[kt&1] (LDS), B frag from registers
    #pragma unroll
    for (int mt = 0; mt < 8; mt++) {
      bf16x8 afrag = *(const bf16x8*)&w_buf[kt & 1][(q * 128 + mt * 16 + c15) * 8];
      acc[mt] = __builtin_amdgcn_mfma_f32_16x16x32_bf16(afrag, pk.h, acc[mt], 0, 0, 0);
    }

    // rotate pipeline slots
    a00 = b00; a01 = b01; a10 = b10; a11 = b11;
    if (HAVE2) { b00 = n00; b01 = n01; b10 = n10; b11 = n11; }
  };

  for (int p = 0; p < 8; ++p) {
    body(p * 4 + 0, gcur, false, true, true);
    body(p * 4 + 1, gcur, false, true, true);
    gnext = make_geo(crd[p + 1][spos]);
    body(p * 4 + 2, gnext, false, true, true);
    body(p * 4 + 3, gnext, false, true, true);
    gcur = gnext;
  }
  body(32, gcur, false, true, true);
  body(33, gcur, false, true, true);
  body(34, gcur, false, true, false);
  body(35, gcur, true, false, false);

  // ---- epilogue
  {
    const int ho = h0 + wave, wo = w0 + c15;
    #pragma unroll
    for (int mt = 0; mt < 8; mt++) {
      #pragma unroll
      for (int r = 0; r < 4; r++) {
        int ch = mt * 16 + q * 4 + r;
        out[((size_t)b * C2 + ch) * HWSZ + ho * WW + wo] = acc[mt][r] + bias[ch];
      }
    }
  }
}

// ---------------------------------------------------------------------------
extern "C" void kernel_launch(void* const* d_in, const int* in_sizes, int n_in,
                              void* d_out, int out_size, void* d_ws, size_t ws_size,
                              hipStream_t stream) {
  const float* x    = (const float*)d_in[0];   // (16,128,80,80)
  const float* ow   = (const float*)d_in[1];   // (18,128,3,3)
  const float* ob   = (const float*)d_in[2];   // (18,)
  const float* wgt  = (const float*)d_in[3];   // (128,128,3,3)
  const float* bias = (const float*)d_in[4];   // (128,)
  float* out = (float*)d_out;                  // (16,128,80,80)

  // workspace layout (xt first for 16B alignment)
  ushort* xt   = (ushort*)d_ws;                          // 26.2 MB
  float*  offs = (float*)((char*)d_ws + 26214400);       // 7.37 MB
  ushort* wbf  = (ushort*)((char*)d_ws + 26214400 + 7372800);           // 288 KB
  ushort* wobf = (ushort*)((char*)d_ws + 26214400 + 7372800 + 294912);  // 72 KB

  xpose_prep_kernel<<<dim3(3920), dim3(256), 0, stream>>>(x, xt, wgt, ow, wbf, wobf);
  offset_mfma_kernel<<<dim3(1600), dim3(256), 0, stream>>>(xt, wobf, ob, offs);
  dconv_mfma_kernel<<<dim3(1600), dim3(256), 0, stream>>>(xt, offs, wbf, bias, out);
}

// Round 4
// 283.162 us; speedup vs baseline: 1.2362x; 1.0218x over previous
//
#include <hip/hip_runtime.h>

// Problem constants (B=16, C1=C2=128, H=W=80, K=3, pad=1, stride=1)
#define HH 80
#define WW 80
#define C1 128
#define C2 128
#define NB 16
#define HWSZ 6400      // 80*80
#define KKT 1152       // C1*9 (GEMM K, reordered as k' = p*128 + c)

typedef __attribute__((ext_vector_type(8))) short bf16x8;
typedef __attribute__((ext_vector_type(4))) float f32x4;

__device__ inline ushort f2bf(float f) {
  unsigned u = __float_as_uint(f);
  return (ushort)((u + 0x7FFFu + ((u >> 16) & 1u)) >> 16);
}

// packed f32x2 -> bf16x2 (RNE, identical rounding to f2bf)
__device__ inline uint cvtpk(float lo, float hi) {
  uint r;
  asm("v_cvt_pk_bf16_f32 %0, %1, %2" : "=v"(r) : "v"(lo), "v"(hi));
  return r;
}
__device__ inline float bfu_lo(uint w) { return __uint_as_float(w << 16); }
__device__ inline float bfu_hi(uint w) { return __uint_as_float(w & 0xFFFF0000u); }

// async global->LDS, 16B per lane, LDS dest = wave-uniform base (+lane*16 by HW)
__device__ inline void gload_lds16(const ushort* g, ushort* l) {
  __builtin_amdgcn_global_load_lds(
      (const __attribute__((address_space(1))) void*)g,
      (__attribute__((address_space(3))) void*)l, 16, 0, 0);
}

// ---------------------------------------------------------------------------
// Kernel A+B merged: transpose x -> xt (blocks 0..3199) and weight prep
// (blocks 3200..3919).
// ---------------------------------------------------------------------------
__global__ __launch_bounds__(256) void xpose_prep_kernel(
    const float* __restrict__ x, ushort* __restrict__ xt,
    const float* __restrict__ w, const float* __restrict__ ow,
    ushort* __restrict__ wbf, ushort* __restrict__ wobf) {
  __shared__ float ts[64][65];
  const int idx = blockIdx.x;
  const int tid = threadIdx.x;

  if (idx < 3200) {
    const int b = idx / 200;
    const int rem = idx % 200;
    const int c0 = (rem / 100) * 64;
    const int hw0 = (rem % 100) * 64;
    const int lane = tid & 63;

    #pragma unroll
    for (int it = 0; it < 16; it++) {
      int cl = (tid >> 6) + it * 4;
      ts[cl][lane] = x[((size_t)(b * C1 + c0 + cl)) * HWSZ + hw0 + lane];
    }
    __syncthreads();

    #pragma unroll
    for (int it = 0; it < 2; it++) {
      int u = tid + it * 256;
      int j = u >> 3, cg = u & 7;
      union { uint4 v; uint d[4]; } pk;
      #pragma unroll
      for (int m = 0; m < 4; m++)
        pk.d[m] = cvtpk(ts[cg * 8 + 2 * m][j], ts[cg * 8 + 2 * m + 1][j]);
      *(uint4*)(xt + ((size_t)b * HWSZ + hw0 + j) * C1 + c0 + cg * 8) = pk.v;
    }
  } else {
    int o = (idx - 3200) * 256 + tid;            // 0..184319
    if (o < C2 * KKT) {
      int j  = o & 7;
      int ch = (o >> 3) & 127;
      int kt = o >> 12;
      int kg = (o >> 10) & 3;
      int kprime = kt * 32 + kg * 8 + j;
      int p = kprime >> 7;
      int c = kprime & 127;
      wbf[o] = f2bf(w[(size_t)ch * KKT + c * 9 + p]);
    } else {
      int o2 = o - C2 * KKT;
      int j  = o2 & 7;
      int ch = (o2 >> 3) & 31;
      int kt = o2 >> 10;
      int kg = (o2 >> 8) & 3;
      int kprime = kt * 32 + kg * 8 + j;
      int p = kprime >> 7;
      int c = kprime & 127;
      wobf[o2] = (ch < 18) ? f2bf(ow[(size_t)ch * KKT + c * 9 + p]) : (ushort)0;
    }
  }
}

// ---------------------------------------------------------------------------
// Kernel C (fused, split-K): 8 waves per block.  wave = (half, row):
//   half = wave>>2 owns K-chunks [half*18, half*18+18)
//   row  = wave&3  owns tile row h0+row (16 positions)
// Phase 0: offset conv partials (barrier-free, shifted loads, wobf from
//          global: 2 KB/chunk shared by ALL blocks -> L1/L2-hot).
// Phase A: combine offset partials (LDS) -> bilinear coords (crd).
// Main:    each half runs an 18-chunk bilinear+MFMA loop (round-1 structure,
//          LDS-staged double-buffered weights), halving the serial
//          dependency chain and doubling independent gather streams.
// Combine: half-1 writes acc to LDS (bank-swizzled), half-0 adds + stores.
// ---------------------------------------------------------------------------
struct Geo { float f00, f01, f10, f11; int o00, o01, o10, o11; };

__device__ inline Geo make_geo(float4 cd) {
  Geo g;
  int y0 = (int)cd.x, x0 = (int)cd.y;
  float wy1 = cd.z, wx1 = cd.w;
  float fy0 = ((unsigned)y0 < (unsigned)HH) ? (1.f - wy1) : 0.f;
  float fy1 = ((unsigned)(y0 + 1) < (unsigned)HH) ? wy1 : 0.f;
  float fx0 = ((unsigned)x0 < (unsigned)WW) ? (1.f - wx1) : 0.f;
  float fx1 = ((unsigned)(x0 + 1) < (unsigned)WW) ? wx1 : 0.f;
  g.f00 = fy0 * fx0; g.f01 = fy0 * fx1;
  g.f10 = fy1 * fx0; g.f11 = fy1 * fx1;
  int r0 = min(max(y0, 0), HH - 1), r1 = min(max(y0 + 1, 0), HH - 1);
  int q0 = min(max(x0, 0), WW - 1), q1 = min(max(x0 + 1, 0), WW - 1);
  g.o00 = (r0 * WW + q0) * C1; g.o01 = (r0 * WW + q1) * C1;
  g.o10 = (r1 * WW + q0) * C1; g.o11 = (r1 * WW + q1) * C1;
  return g;
}

__global__ __launch_bounds__(512) void dconv_fused_kernel(
    const ushort* __restrict__ xt, const ushort* __restrict__ wobf,
    const float* __restrict__ ob, const ushort* __restrict__ wbf,
    const float* __restrict__ bias, float* __restrict__ out) {
  const int bid = blockIdx.x;                    // 0..1599 (bid&7 = b&7: XCD/batch L2 locality)
  const int b = bid & 15;
  const int tile = bid >> 4;                     // 0..99
  const int h0 = (tile / 5) * 4;
  const int w0 = (tile % 5) * 16;
  const int tid = threadIdx.x;
  const int lane = tid & 63;
  const int wave = tid >> 6;                     // 0..7
  const int half = wave >> 2;                    // K-half
  const int row  = wave & 3;                     // tile row
  const int q = lane >> 4, c15 = lane & 15;
  const int spos = row * 16 + c15;
  const int base = half * 18;

  __shared__ ushort w_buf[2][2][4096];           // 32 KB  [half][dbuf]
  __shared__ float4 crd[9][64];                  // 9216 B
  __shared__ float  obuf[2][18][64];             // 9216 B offset-conv partials

  const ushort* xtb = xt + (size_t)b * HWSZ * C1;

  auto shifted_load = [&](int kt) -> uint4 {
    const int p = kt >> 2, c0 = (kt & 3) << 5;
    const int r = h0 + row + (p / 3) - 1;
    const int col = w0 + c15 + (p % 3) - 1;
    uint4 v = {0u, 0u, 0u, 0u};
    if ((unsigned)r < (unsigned)HH && (unsigned)col < (unsigned)WW)
      v = *(const uint4*)(xtb + ((size_t)r * WW + col) * C1 + c0 + q * 8);
    return v;
  };

  // ===== Phase 0: offset-conv partials for K-chunks [base, base+18) =====
  {
    f32x4 acc0 = {0.f, 0.f, 0.f, 0.f}, acc1 = {0.f, 0.f, 0.f, 0.f};
    uint4 cv = shifted_load(base);

    #pragma unroll 2
    for (int i = 0; i < 18; ++i) {
      const int kt = base + i;
      uint4 nv = {0u, 0u, 0u, 0u};
      if (i < 17) nv = shifted_load(kt + 1);

      bf16x8 a0 = *(const bf16x8*)(wobf + ((size_t)kt * 128 + q * 32 + c15) * 8);
      bf16x8 a1 = *(const bf16x8*)(wobf + ((size_t)kt * 128 + q * 32 + 16 + c15) * 8);
      union { uint4 v; bf16x8 h; } bu; bu.v = cv;
      acc0 = __builtin_amdgcn_mfma_f32_16x16x32_bf16(a0, bu.h, acc0, 0, 0, 0);
      acc1 = __builtin_amdgcn_mfma_f32_16x16x32_bf16(a1, bu.h, acc1, 0, 0, 0);
      cv = nv;
    }

    // D layout: col = c15 (pos), row = q*4+r (ch)
    #pragma unroll
    for (int r = 0; r < 4; r++)
      obuf[half][q * 4 + r][spos] = acc0[r];
    if (q == 0) {
      obuf[half][16][spos] = acc1[0];
      obuf[half][17][spos] = acc1[1];
    }
  }
  __syncthreads();

  // ===== Phase A: combine partials -> bilinear coords =====
  {
    const int ho = h0 + row, wo = w0 + c15;
    #pragma unroll
    for (int p = 0; p < 9; ++p) {
      if ((p & 1) == half && ((p >> 1) & 3) == q) {
        float dy = obuf[0][2 * p][spos] + obuf[1][2 * p][spos] + ob[2 * p];
        float dx = obuf[0][2 * p + 1][spos] + obuf[1][2 * p + 1][spos] + ob[2 * p + 1];
        float py = (float)(ho - 1 + p / 3) + dy;
        float px = (float)(wo - 1 + p % 3) + dx;
        float y0f = floorf(py), x0f = floorf(px);
        crd[p][spos] = make_float4(y0f, x0f, py - y0f, px - x0f);
      }
    }
  }

  auto stage = [&](int kn, int buf) {
    #pragma unroll
    for (int jj = 0; jj < 2; ++jj)
      gload_lds16(wbf + ((size_t)kn * 512 + row * 128 + jj * 64 + lane) * 8,
                  &w_buf[half][buf][(row * 128 + jj * 64) * 8]);
  };

  auto gload = [&](const Geo& gg, int c0,
                   uint4& r00, uint4& r01, uint4& r10, uint4& r11) {
    const ushort* cp = xtb + c0 + q * 8;
    r00 = *(const uint4*)(cp + gg.o00);
    r01 = *(const uint4*)(cp + gg.o01);
    r10 = *(const uint4*)(cp + gg.o10);
    r11 = *(const uint4*)(cp + gg.o11);
  };

  stage(base, 0);
  __syncthreads();   // crd visible + stage-0 landed (vmcnt/lgkm drain)

  // ===== Main: 18-chunk bilinear + MFMA (round-1 loop structure) =====
  f32x4 acc[8];
  #pragma unroll
  for (int mt = 0; mt < 8; mt++) acc[mt] = (f32x4){0.f, 0.f, 0.f, 0.f};

  Geo g = make_geo(crd[base >> 2][spos]);
  uint4 ca00, ca01, ca10, ca11;
  gload(g, (base & 3) << 5, ca00, ca01, ca10, ca11);

  #pragma unroll 2
  for (int i = 0; i < 18; ++i) {
    const int kt = base + i;
    const int cur = i & 1;

    Geo gn = g;
    uint4 na00 = {}, na01 = {}, na10 = {}, na11 = {};
    if (i < 17) {
      const int kn = kt + 1;
      stage(kn, cur ^ 1);
      if ((kn & 3) == 0) gn = make_geo(crd[kn >> 2][spos]);
      gload(gn, (kn & 3) << 5, na00, na01, na10, na11);
    }

    // flat 4-corner bilinear; result IS the MFMA B fragment
    union { uint4 v; uint d[4]; } u00, u01, u10, u11;
    union { uint4 v; uint d[4]; bf16x8 h; } pk;
    u00.v = ca00; u01.v = ca01; u10.v = ca10; u11.v = ca11;
    #pragma unroll
    for (int jw = 0; jw < 4; ++jw) {
      float ol = g.f00 * bfu_lo(u00.d[jw]);
      float oh = g.f00 * bfu_hi(u00.d[jw]);
      ol = fmaf(g.f01, bfu_lo(u01.d[jw]), ol);
      oh = fmaf(g.f01, bfu_hi(u01.d[jw]), oh);
      ol = fmaf(g.f10, bfu_lo(u10.d[jw]), ol);
      oh = fmaf(g.f10, bfu_hi(u10.d[jw]), oh);
      ol = fmaf(g.f11, bfu_lo(u11.d[jw]), ol);
      oh = fmaf(g.f11, bfu_hi(u11.d[jw]), oh);
      pk.d[jw] = cvtpk(ol, oh);
    }

    #pragma unroll
    for (int mt = 0; mt < 8; mt++) {
      bf16x8 afrag = *(const bf16x8*)&w_buf[half][cur][(q * 128 + mt * 16 + c15) * 8];
      acc[mt] = __builtin_amdgcn_mfma_f32_16x16x32_bf16(afrag, pk.h, acc[mt], 0, 0, 0);
    }

    __syncthreads();
    g = gn;
    ca00 = na00; ca01 = na01; ca10 = na10; ca11 = na11;
  }

  // ===== Combine halves (reuse w_buf as 32 KB f32 scratch) =====
  float* pbuf = (float*)&w_buf[0][0][0];         // [pos][128ch], XOR-swizzled
  const int swz = (c15 & 7) << 2;                // break 128-f32 stride conflicts

  if (half == 1) {
    #pragma unroll
    for (int mt = 0; mt < 8; mt++) {
      const int chb = mt * 16 + q * 4;
      #pragma unroll
      for (int r = 0; r < 4; r++)
        pbuf[spos * 128 + ((chb + r) ^ swz)] = acc[mt][r];
    }
  }
  __syncthreads();
  if (half == 0) {
    const int ho = h0 + row, wo = w0 + c15;
    #pragma unroll
    for (int mt = 0; mt < 8; mt++) {
      const int chb = mt * 16 + q * 4;
      f32x4 part = *(const f32x4*)&pbuf[spos * 128 + (chb ^ swz)];
      #pragma unroll
      for (int r = 0; r < 4; r++) {
        const int ch = chb + r;
        out[((size_t)b * C2 + ch) * HWSZ + ho * WW + wo] =
            acc[mt][r] + part[r] + bias[ch];
      }
    }
  }
}

// ---------------------------------------------------------------------------
extern "C" void kernel_launch(void* const* d_in, const int* in_sizes, int n_in,
                              void* d_out, int out_size, void* d_ws, size_t ws_size,
                              hipStream_t stream) {
  const float* x    = (const float*)d_in[0];   // (16,128,80,80)
  const float* ow   = (const float*)d_in[1];   // (18,128,3,3)
  const float* ob   = (const float*)d_in[2];   // (18,)
  const float* wgt  = (const float*)d_in[3];   // (128,128,3,3)
  const float* bias = (const float*)d_in[4];   // (128,)
  float* out = (float*)d_out;                  // (16,128,80,80)

  // workspace layout
  ushort* xt   = (ushort*)d_ws;                          // 26.2 MB
  ushort* wbf  = (ushort*)((char*)d_ws + 26214400);      // 288 KB
  ushort* wobf = (ushort*)((char*)d_ws + 26214400 + 294912);  // 72 KB

  xpose_prep_kernel<<<dim3(3920), dim3(256), 0, stream>>>(x, xt, wgt, ow, wbf, wobf);
  dconv_fused_kernel<<<dim3(1600), dim3(512), 0, stream>>>(xt, wobf, ob, wbf, bias, out);
}